// Round 1
// baseline (476.710 us; speedup 1.0000x reference)
//
#include <hip/hip_runtime.h>

// GCN3: 3x { segment_sum over edges + Linear } with LeakyReLU(0.1) between.
// N=100000 nodes, E=1600000 edges, F: 32 -> 32 -> 32 -> 16 (layer3 transform-first).

template <int F>
__global__ void scatter_kernel(const float* __restrict__ h,
                               const int* __restrict__ src,
                               const int* __restrict__ dst,
                               float* __restrict__ agg,
                               int n_edges) {
    int gid = blockIdx.x * blockDim.x + threadIdx.x;
    int e = gid / F;          // F is power of two -> shift
    int f = gid & (F - 1);
    if (e >= n_edges) return;
    int s = src[e];
    int d = dst[e];
    float v = h[(long long)s * F + f];
    unsafeAtomicAdd(&agg[(long long)d * F + f], v);
}

// out[n][16] = b3[j] broadcast (bias pre-init; scatter adds on top)
__global__ void init_out_kernel(float* __restrict__ out,
                                const float* __restrict__ b,
                                int total) {
    int gid = blockIdx.x * blockDim.x + threadIdx.x;
    if (gid < total) out[gid] = b[gid & 15];
}

template <int IN, int OUT, bool RELU, bool BIAS>
__global__ void dense_kernel(const float* __restrict__ in,
                             const float* __restrict__ W,
                             const float* __restrict__ b,
                             float* __restrict__ out,
                             int n) {
    __shared__ float sW[IN * OUT];
    __shared__ float sb[OUT > 0 ? OUT : 1];
    for (int i = threadIdx.x; i < IN * OUT; i += blockDim.x) sW[i] = W[i];
    if (BIAS) {
        for (int i = threadIdx.x; i < OUT; i += blockDim.x) sb[i] = b[i];
    }
    __syncthreads();

    int node = blockIdx.x * blockDim.x + threadIdx.x;
    if (node >= n) return;

    float row[IN];
    const float4* rp = (const float4*)(in + (long long)node * IN);
#pragma unroll
    for (int k4 = 0; k4 < IN / 4; ++k4) {
        float4 v = rp[k4];
        row[k4 * 4 + 0] = v.x;
        row[k4 * 4 + 1] = v.y;
        row[k4 * 4 + 2] = v.z;
        row[k4 * 4 + 3] = v.w;
    }

    float acc[OUT];
#pragma unroll
    for (int j = 0; j < OUT; ++j) acc[j] = BIAS ? sb[j] : 0.0f;

#pragma unroll
    for (int k = 0; k < IN; ++k) {
        float a = row[k];
#pragma unroll
        for (int j = 0; j < OUT; ++j) acc[j] += a * sW[k * OUT + j];
    }

    float4* op = (float4*)(out + (long long)node * OUT);
#pragma unroll
    for (int j4 = 0; j4 < OUT / 4; ++j4) {
        float4 v;
        float x0 = acc[j4 * 4 + 0];
        float x1 = acc[j4 * 4 + 1];
        float x2 = acc[j4 * 4 + 2];
        float x3 = acc[j4 * 4 + 3];
        if (RELU) {
            x0 = x0 >= 0.0f ? x0 : 0.1f * x0;
            x1 = x1 >= 0.0f ? x1 : 0.1f * x1;
            x2 = x2 >= 0.0f ? x2 : 0.1f * x2;
            x3 = x3 >= 0.0f ? x3 : 0.1f * x3;
        }
        v.x = x0; v.y = x1; v.z = x2; v.w = x3;
        op[j4] = v;
    }
}

extern "C" void kernel_launch(void* const* d_in, const int* in_sizes, int n_in,
                              void* d_out, int out_size, void* d_ws, size_t ws_size,
                              hipStream_t stream) {
    const float* x  = (const float*)d_in[0];
    const int* src  = (const int*)d_in[1];
    const int* dst  = (const int*)d_in[2];
    const float* W1 = (const float*)d_in[3];
    const float* b1 = (const float*)d_in[4];
    const float* W2 = (const float*)d_in[5];
    const float* b2 = (const float*)d_in[6];
    const float* W3 = (const float*)d_in[7];
    const float* b3 = (const float*)d_in[8];
    float* out = (float*)d_out;

    const int n  = in_sizes[0] / 32;   // 100000
    const int nE = in_sizes[1];        // 1600000

    float* agg = (float*)d_ws;                 // n*32 floats (also holds n*16 t3)
    float* h   = agg + (size_t)n * 32;         // n*32 floats

    const int BLK = 256;
    const int scat32_grid = (nE * 32 + BLK - 1) / BLK;
    const int scat16_grid = (nE * 16 + BLK - 1) / BLK;
    const int node_grid   = (n + BLK - 1) / BLK;

    // ---- Layer 1: agg = scatter(x); h = leaky(agg @ W1 + b1)
    hipMemsetAsync(agg, 0, (size_t)n * 32 * sizeof(float), stream);
    scatter_kernel<32><<<scat32_grid, BLK, 0, stream>>>(x, src, dst, agg, nE);
    dense_kernel<32, 32, true, true><<<node_grid, BLK, 0, stream>>>(agg, W1, b1, h, n);

    // ---- Layer 2: agg = scatter(h); h = leaky(agg @ W2 + b2)
    hipMemsetAsync(agg, 0, (size_t)n * 32 * sizeof(float), stream);
    scatter_kernel<32><<<scat32_grid, BLK, 0, stream>>>(h, src, dst, agg, nE);
    dense_kernel<32, 32, true, true><<<node_grid, BLK, 0, stream>>>(agg, W2, b2, h, n);

    // ---- Layer 3 (transform-first): t3 = h @ W3 (n x 16); out = b3 + scatter(t3)
    dense_kernel<32, 16, false, false><<<node_grid, BLK, 0, stream>>>(h, W3, nullptr, agg, n);
    init_out_kernel<<<(n * 16 + BLK - 1) / BLK, BLK, 0, stream>>>(out, b3, n * 16);
    scatter_kernel<16><<<scat16_grid, BLK, 0, stream>>>(agg, src, dst, out, nE);
}

// Round 2
// 379.977 us; speedup vs baseline: 1.2546x; 1.2546x over previous
//
#include <hip/hip_runtime.h>

// GCN3: 3x { segment_sum over edges + Linear } with LeakyReLU(0.1).
// Strategy: build CSR (counting sort by dst) once per call, then 3x gather-sum
// (atomic-free) + tiny dense kernels. Layer 3 transforms first (32->16) so the
// final gather is 16-wide with bias folded in.

#define SCAN_BLOCK 256
#define SCAN_EPT   8
#define SCAN_TILE  (SCAN_BLOCK * SCAN_EPT)   // 2048 elements per scan block

// ---------------- CSR build ----------------

__global__ void hist_kernel(const int* __restrict__ dst, int* __restrict__ deg, int nE) {
    int e = blockIdx.x * blockDim.x + threadIdx.x;
    if (e < nE) atomicAdd(&deg[dst[e]], 1);
}

__global__ void scan1_kernel(const int* __restrict__ deg, int* __restrict__ off,
                             int* __restrict__ bsums, int n) {
    __shared__ int lds[SCAN_BLOCK];
    int tid  = threadIdx.x;
    int base = blockIdx.x * SCAN_TILE + tid * SCAN_EPT;
    int v[SCAN_EPT];
    int run = 0;
#pragma unroll
    for (int i = 0; i < SCAN_EPT; ++i) {
        int t = (base + i < n) ? deg[base + i] : 0;
        v[i] = run;           // exclusive within thread
        run += t;
    }
    lds[tid] = run;
    __syncthreads();
    // inclusive Hillis-Steele across the block
    for (int o = 1; o < SCAN_BLOCK; o <<= 1) {
        int t = (tid >= o) ? lds[tid - o] : 0;
        __syncthreads();
        lds[tid] += t;
        __syncthreads();
    }
    int toff = (tid > 0) ? lds[tid - 1] : 0;
#pragma unroll
    for (int i = 0; i < SCAN_EPT; ++i)
        if (base + i < n) off[base + i] = v[i] + toff;
    if (tid == SCAN_BLOCK - 1) bsums[blockIdx.x] = lds[tid];
}

__global__ void scan2_kernel(int* __restrict__ bsums, int nb) {
    __shared__ int lds[SCAN_BLOCK];
    int tid = threadIdx.x;
    lds[tid] = (tid < nb) ? bsums[tid] : 0;
    __syncthreads();
    for (int o = 1; o < SCAN_BLOCK; o <<= 1) {
        int t = (tid >= o) ? lds[tid - o] : 0;
        __syncthreads();
        lds[tid] += t;
        __syncthreads();
    }
    int ex = (tid > 0) ? lds[tid - 1] : 0;
    if (tid < nb) bsums[tid] = ex;
}

__global__ void scan3_kernel(int* __restrict__ off, const int* __restrict__ bsums, int n) {
    int gid = blockIdx.x * blockDim.x + threadIdx.x;
    if (gid < n) off[gid] += bsums[gid / SCAN_TILE];
}

__global__ void fill_kernel(const int* __restrict__ src, const int* __restrict__ dst,
                            int* __restrict__ cursor, int* __restrict__ perm, int nE) {
    int e = blockIdx.x * blockDim.x + threadIdx.x;
    if (e < nE) {
        int pos = atomicAdd(&cursor[dst[e]], 1);
        perm[pos] = src[e];
    }
}

// ---------------- per-layer kernels ----------------

// agg[node][f] = (BIAS? b[f]:0) + sum over in-edges of t[src][f]
template <int F, bool BIAS>
__global__ void gather_kernel(const float* __restrict__ t, const int* __restrict__ perm,
                              const int* __restrict__ off, const int* __restrict__ deg,
                              const float* __restrict__ b, float* __restrict__ out, int n) {
    int gid  = blockIdx.x * blockDim.x + threadIdx.x;
    int node = gid / F;
    int f    = gid & (F - 1);
    if (node >= n) return;
    int o = off[node];
    int d = deg[node];
    float acc = BIAS ? b[f] : 0.0f;
    int i = 0;
    for (; i + 1 < d; i += 2) {           // two independent gathers in flight
        int s0 = perm[o + i];
        int s1 = perm[o + i + 1];
        float a0 = t[(long long)s0 * F + f];
        float a1 = t[(long long)s1 * F + f];
        acc += a0;
        acc += a1;
    }
    if (i < d) acc += t[(long long)perm[o + i] * F + f];
    out[(long long)node * F + f] = acc;
}

template <int IN, int OUT, bool RELU, bool BIAS>
__global__ void dense_kernel(const float* __restrict__ in,
                             const float* __restrict__ W,
                             const float* __restrict__ b,
                             float* __restrict__ out,
                             int n) {
    __shared__ float sW[IN * OUT];
    __shared__ float sb[OUT];
    for (int i = threadIdx.x; i < IN * OUT; i += blockDim.x) sW[i] = W[i];
    if (BIAS) {
        for (int i = threadIdx.x; i < OUT; i += blockDim.x) sb[i] = b[i];
    }
    __syncthreads();

    int node = blockIdx.x * blockDim.x + threadIdx.x;
    if (node >= n) return;

    float row[IN];
    const float4* rp = (const float4*)(in + (long long)node * IN);
#pragma unroll
    for (int k4 = 0; k4 < IN / 4; ++k4) {
        float4 v = rp[k4];
        row[k4 * 4 + 0] = v.x;
        row[k4 * 4 + 1] = v.y;
        row[k4 * 4 + 2] = v.z;
        row[k4 * 4 + 3] = v.w;
    }

    float acc[OUT];
#pragma unroll
    for (int j = 0; j < OUT; ++j) acc[j] = BIAS ? sb[j] : 0.0f;

#pragma unroll
    for (int k = 0; k < IN; ++k) {
        float a = row[k];
#pragma unroll
        for (int j = 0; j < OUT; ++j) acc[j] += a * sW[k * OUT + j];
    }

    float4* op = (float4*)(out + (long long)node * OUT);
#pragma unroll
    for (int j4 = 0; j4 < OUT / 4; ++j4) {
        float4 v;
        float x0 = acc[j4 * 4 + 0];
        float x1 = acc[j4 * 4 + 1];
        float x2 = acc[j4 * 4 + 2];
        float x3 = acc[j4 * 4 + 3];
        if (RELU) {
            x0 = x0 >= 0.0f ? x0 : 0.1f * x0;
            x1 = x1 >= 0.0f ? x1 : 0.1f * x1;
            x2 = x2 >= 0.0f ? x2 : 0.1f * x2;
            x3 = x3 >= 0.0f ? x3 : 0.1f * x3;
        }
        v.x = x0; v.y = x1; v.z = x2; v.w = x3;
        op[j4] = v;
    }
}

// ---------------- fallback (round-1 atomic path) ----------------

template <int F>
__global__ void scatter_kernel(const float* __restrict__ h,
                               const int* __restrict__ src,
                               const int* __restrict__ dst,
                               float* __restrict__ agg,
                               int n_edges) {
    int gid = blockIdx.x * blockDim.x + threadIdx.x;
    int e = gid / F;
    int f = gid & (F - 1);
    if (e >= n_edges) return;
    float v = h[(long long)src[e] * F + f];
    unsafeAtomicAdd(&agg[(long long)dst[e] * F + f], v);
}

__global__ void init_out_kernel(float* __restrict__ out, const float* __restrict__ b,
                                int total) {
    int gid = blockIdx.x * blockDim.x + threadIdx.x;
    if (gid < total) out[gid] = b[gid & 15];
}

// ---------------- launch ----------------

extern "C" void kernel_launch(void* const* d_in, const int* in_sizes, int n_in,
                              void* d_out, int out_size, void* d_ws, size_t ws_size,
                              hipStream_t stream) {
    const float* x  = (const float*)d_in[0];
    const int* src  = (const int*)d_in[1];
    const int* dst  = (const int*)d_in[2];
    const float* W1 = (const float*)d_in[3];
    const float* b1 = (const float*)d_in[4];
    const float* W2 = (const float*)d_in[5];
    const float* b2 = (const float*)d_in[6];
    const float* W3 = (const float*)d_in[7];
    const float* b3 = (const float*)d_in[8];
    float* out = (float*)d_out;

    const int n  = in_sizes[0] / 32;   // 100000
    const int nE = in_sizes[1];        // 1600000
    const int BLK = 256;
    const int node_grid = (n + BLK - 1) / BLK;
    const int NB = (n + SCAN_TILE - 1) / SCAN_TILE;   // scan blocks (49)

    // workspace layout
    float* agg   = (float*)d_ws;                      // n*32 floats (reused for t3)
    float* h     = agg + (size_t)n * 32;              // n*32 floats
    int*   deg   = (int*)(h + (size_t)n * 32);        // n
    int*   off   = deg + n;                           // n
    int*   cursor= off + n;                           // n
    int*   bsums = cursor + n;                        // SCAN_BLOCK (padded)
    int*   perm  = bsums + SCAN_BLOCK;                // nE
    size_t need  = (size_t)((size_t)n * 64 + 3 * (size_t)n + SCAN_BLOCK + (size_t)nE) * 4;

    if (ws_size >= need && NB <= SCAN_BLOCK) {
        // ---- CSR build (amortized over 3 layers) ----
        hipMemsetAsync(deg, 0, (size_t)n * sizeof(int), stream);
        hist_kernel<<<(nE + BLK - 1) / BLK, BLK, 0, stream>>>(dst, deg, nE);
        scan1_kernel<<<NB, SCAN_BLOCK, 0, stream>>>(deg, off, bsums, n);
        scan2_kernel<<<1, SCAN_BLOCK, 0, stream>>>(bsums, NB);
        scan3_kernel<<<node_grid, BLK, 0, stream>>>(off, bsums, n);
        hipMemcpyAsync(cursor, off, (size_t)n * sizeof(int),
                       hipMemcpyDeviceToDevice, stream);
        fill_kernel<<<(nE + BLK - 1) / BLK, BLK, 0, stream>>>(src, dst, cursor, perm, nE);

        const int g32 = (n * 32 + BLK - 1) / BLK;
        const int g16 = (n * 16 + BLK - 1) / BLK;

        // Layer 1
        gather_kernel<32, false><<<g32, BLK, 0, stream>>>(x, perm, off, deg, nullptr, agg, n);
        dense_kernel<32, 32, true, true><<<node_grid, BLK, 0, stream>>>(agg, W1, b1, h, n);
        // Layer 2
        gather_kernel<32, false><<<g32, BLK, 0, stream>>>(h, perm, off, deg, nullptr, agg, n);
        dense_kernel<32, 32, true, true><<<node_grid, BLK, 0, stream>>>(agg, W2, b2, h, n);
        // Layer 3: transform first (32->16), then gather with bias
        dense_kernel<32, 16, false, false><<<node_grid, BLK, 0, stream>>>(h, W3, nullptr, agg, n);
        gather_kernel<16, true><<<g16, BLK, 0, stream>>>(agg, perm, off, deg, b3, out, n);
    } else {
        // ---- fallback: atomic scatter path ----
        const int scat32_grid = (nE * 32 + BLK - 1) / BLK;
        const int scat16_grid = (nE * 16 + BLK - 1) / BLK;
        hipMemsetAsync(agg, 0, (size_t)n * 32 * sizeof(float), stream);
        scatter_kernel<32><<<scat32_grid, BLK, 0, stream>>>(x, src, dst, agg, nE);
        dense_kernel<32, 32, true, true><<<node_grid, BLK, 0, stream>>>(agg, W1, b1, h, n);
        hipMemsetAsync(agg, 0, (size_t)n * 32 * sizeof(float), stream);
        scatter_kernel<32><<<scat32_grid, BLK, 0, stream>>>(h, src, dst, agg, nE);
        dense_kernel<32, 32, true, true><<<node_grid, BLK, 0, stream>>>(agg, W2, b2, h, n);
        dense_kernel<32, 16, false, false><<<node_grid, BLK, 0, stream>>>(h, W3, nullptr, agg, n);
        init_out_kernel<<<(n * 16 + BLK - 1) / BLK, BLK, 0, stream>>>(out, b3, n * 16);
        scatter_kernel<16><<<scat16_grid, BLK, 0, stream>>>(agg, src, dst, out, nE);
    }
}